// Round 6
// baseline (826.765 us; speedup 1.0000x reference)
//
#include <hip/hip_runtime.h>
#include <stdint.h>

typedef uint32_t u32;
typedef unsigned long long u64;

#define NEGV (-1e9f)
#define NCAND 16
#define LISTCAP 256
#define RSCALE 2048.0f
#define RINV   (1.0f / 2048.0f)
#define DELTA  4e-3f

typedef __attribute__((ext_vector_type(8))) _Float16 half8;
typedef __attribute__((ext_vector_type(4))) float f32x4;

__device__ __forceinline__ u32 f2ord(float f) {
  u32 x = __float_as_uint(f);
  return (x & 0x80000000u) ? ~x : (x | 0x80000000u);
}
__device__ __forceinline__ float ord2f(u32 u) {
  u32 x = (u & 0x80000000u) ? (u ^ 0x80000000u) : ~u;
  return __uint_as_float(x);
}

// async global->LDS, 16B per lane. LDS dest = wave-uniform base + lane*16.
__device__ __forceinline__ void gl_lds16(const unsigned short* g, unsigned short* l) {
  __builtin_amdgcn_global_load_lds(
      (const __attribute__((address_space(1))) u32*)g,
      (__attribute__((address_space(3))) u32*)l, 16, 0, 0);
}

// ---- mask packer: int32 mask [2][2048][4096] -> u64 bits [2][2048][64] ----
__global__ __launch_bounds__(256)
void pack_mask(const int* __restrict__ mask, u64* __restrict__ mbits) {
  int w = blockIdx.x * 256 + threadIdx.x;
  const int4* p = (const int4*)(mask + (size_t)w * 64);
  u64 bits = 0;
#pragma unroll
  for (int j = 0; j < 16; ++j) {
    int4 m = p[j];
    if (m.x) bits |= 1ull << (j * 4 + 0);
    if (m.y) bits |= 1ull << (j * 4 + 1);
    if (m.z) bits |= 1ull << (j * 4 + 2);
    if (m.w) bits |= 1ull << (j * 4 + 3);
  }
  mbits[w] = bits;
}

// ---- C[M x 512] = A[M x 512] @ W[512 x 512] + bias (row-major out) ----
__global__ __launch_bounds__(256)
void gemm_bias(const float* __restrict__ A, const float* __restrict__ W,
               const float* __restrict__ bias, float* __restrict__ C) {
  __shared__ float As[16][68];
  __shared__ float Bs[16][64];
  const int tid = threadIdx.x;
  const int tx = tid & 15, ty = tid >> 4;
  const int n0 = blockIdx.x << 6, m0 = blockIdx.y << 6;
  float c[4][4] = {};
  for (int k0 = 0; k0 < 512; k0 += 16) {
    {
      const int row = tid >> 2, kp = (tid & 3) << 2;
      float4 av = *(const float4*)&A[(size_t)(m0 + row) * 512 + k0 + kp];
      As[kp + 0][row] = av.x;
      As[kp + 1][row] = av.y;
      As[kp + 2][row] = av.z;
      As[kp + 3][row] = av.w;
      const int kk = tid >> 4, np = (tid & 15) << 2;
      *(float4*)&Bs[kk][np] = *(const float4*)&W[(size_t)(k0 + kk) * 512 + n0 + np];
    }
    __syncthreads();
#pragma unroll
    for (int kk = 0; kk < 16; ++kk) {
      float4 a = *(const float4*)&As[kk][ty << 2];
      float4 b = *(const float4*)&Bs[kk][tx << 2];
      c[0][0] += a.x * b.x; c[0][1] += a.x * b.y; c[0][2] += a.x * b.z; c[0][3] += a.x * b.w;
      c[1][0] += a.y * b.x; c[1][1] += a.y * b.y; c[1][2] += a.y * b.z; c[1][3] += a.y * b.w;
      c[2][0] += a.z * b.x; c[2][1] += a.z * b.y; c[2][2] += a.z * b.z; c[2][3] += a.z * b.w;
      c[3][0] += a.w * b.x; c[3][1] += a.w * b.y; c[3][2] += a.w * b.z; c[3][3] += a.w * b.w;
    }
    __syncthreads();
  }
  float4 bv = *(const float4*)&bias[n0 + (tx << 2)];
#pragma unroll
  for (int i = 0; i < 4; ++i) {
    float4 o;
    o.x = c[i][0] + bv.x; o.y = c[i][1] + bv.y;
    o.z = c[i][2] + bv.z; o.w = c[i][3] + bv.w;
    *(float4*)&C[(size_t)(m0 + (ty << 2) + i) * 512 + n0 + (tx << 2)] = o;
  }
}

// ---- same GEMM math; epilogue writes (a) fp32 head-major plane Pf (exact
// projection values, used for candidate rescoring), (b) f16 hi plane,
// (c) f16 residual*2^11 plane (kept f16-normal; unscaled residuals ~1e-4 are
// f16-denormal and flush in the MFMA). Layout for all three:
// P[(m>>qsh)*8 + h][m & (QL-1)][d], d=0..63. ----
__global__ __launch_bounds__(256)
void gemm_bias_split(const float* __restrict__ A, const float* __restrict__ W,
                     const float* __restrict__ bias,
                     unsigned short* __restrict__ Ph, unsigned short* __restrict__ Pl,
                     float* __restrict__ Pf, int qsh) {
  __shared__ float As[16][68];
  __shared__ float Bs[16][64];
  const int tid = threadIdx.x;
  const int tx = tid & 15, ty = tid >> 4;
  const int n0 = blockIdx.x << 6, m0 = blockIdx.y << 6;
  float c[4][4] = {};
  for (int k0 = 0; k0 < 512; k0 += 16) {
    {
      const int row = tid >> 2, kp = (tid & 3) << 2;
      float4 av = *(const float4*)&A[(size_t)(m0 + row) * 512 + k0 + kp];
      As[kp + 0][row] = av.x;
      As[kp + 1][row] = av.y;
      As[kp + 2][row] = av.z;
      As[kp + 3][row] = av.w;
      const int kk = tid >> 4, np = (tid & 15) << 2;
      *(float4*)&Bs[kk][np] = *(const float4*)&W[(size_t)(k0 + kk) * 512 + n0 + np];
    }
    __syncthreads();
#pragma unroll
    for (int kk = 0; kk < 16; ++kk) {
      float4 a = *(const float4*)&As[kk][ty << 2];
      float4 b = *(const float4*)&Bs[kk][tx << 2];
      c[0][0] += a.x * b.x; c[0][1] += a.x * b.y; c[0][2] += a.x * b.z; c[0][3] += a.x * b.w;
      c[1][0] += a.y * b.x; c[1][1] += a.y * b.y; c[1][2] += a.y * b.z; c[1][3] += a.y * b.w;
      c[2][0] += a.z * b.x; c[2][1] += a.z * b.y; c[2][2] += a.z * b.z; c[2][3] += a.z * b.w;
      c[3][0] += a.w * b.x; c[3][1] += a.w * b.y; c[3][2] += a.w * b.z; c[3][3] += a.w * b.w;
    }
    __syncthreads();
  }
  float4 bv = *(const float4*)&bias[n0 + (tx << 2)];
  float bvv[4] = {bv.x, bv.y, bv.z, bv.w};
  const int h = blockIdx.x;           // n0 = h*64 since tile width == head width
  const int QL = 1 << qsh;
#pragma unroll
  for (int i = 0; i < 4; ++i) {
    const int m = m0 + (ty << 2) + i;
    const size_t base =
        (((size_t)((m >> qsh) * 8 + h)) * QL + (m & (QL - 1))) * 64 + (tx << 2);
    u64 hb = 0, lb = 0;
    float fv[4];
#pragma unroll
    for (int j = 0; j < 4; ++j) {
      float val = c[i][j] + bvv[j];
      fv[j] = val;
      union { _Float16 f; unsigned short u; } ch, cl;
      ch.f = (_Float16)val;                       // RN fp32->fp16
      float hf = (float)ch.f;
      cl.f = (_Float16)((val - hf) * RSCALE);     // exact diff, scaled to normal range
      hb |= (u64)ch.u << (16 * j);
      lb |= (u64)cl.u << (16 * j);
    }
    float4 fo;
    fo.x = fv[0]; fo.y = fv[1]; fo.z = fv[2]; fo.w = fv[3];
    *(u64*)&Ph[base] = hb;
    *(u64*)&Pl[base] = lb;
    *(float4*)&Pf[base] = fo;
  }
}

// ---- scores via MFMA f16x3 with scaled residuals: 128(q) x 128(s) tile per
// block, 4 waves each computing a 64x64 quadrant with mfma_f32_16x16x32_f16.
//   accB = Qh*Kh; accS = Qh*Kl' + Ql'*Kh; s = (accB + accS/2^11) * 0.125
// Scores used for candidate DISCOVERY only (DELTA-margined); selection +
// softmax use exact fp32/f64 rescoring in topk_ctx. ----
__global__ __launch_bounds__(256, 2)
void score_mfma(const unsigned short* __restrict__ qh, const unsigned short* __restrict__ ql,
                const unsigned short* __restrict__ kh, const unsigned short* __restrict__ kl,
                const u64* __restrict__ mbits, float* __restrict__ sbuf,
                float* __restrict__ segmax, int sl0) {
  __shared__ alignas(16) unsigned short lds[4][128][64];  // qh, ql, kh, kl = 64 KB
  const int sl = sl0 + blockIdx.z;
  const int b = sl >> 3, h = sl & 7;
  const int s0 = blockIdx.x << 7, q0 = blockIdx.y << 7;
  const int tid = threadIdx.x;
  const int lane = tid & 63, w = tid >> 6;

  const unsigned short* q0p = qh + ((size_t)sl * 2048 + q0) * 64;
  const unsigned short* q1p = ql + ((size_t)sl * 2048 + q0) * 64;
  const unsigned short* k0p = kh + ((size_t)h * 4096 + s0) * 64;
  const unsigned short* k1p = kl + ((size_t)h * 4096 + s0) * 64;

  // stage: wave w stages rows [w*32, w*32+32) of each plane; 8 rows (1 KB) per
  // instruction. LDS[row][p] <- global[row][p ^ (row&7)] (16B chunk units).
  {
    const int r8 = lane >> 3, pc = lane & 7;
#pragma unroll
    for (int u = 0; u < 4; ++u) {
      const int row = (w << 5) + (u << 3) + r8;
      const size_t src = (size_t)row * 64 + (size_t)((pc ^ (row & 7)) << 3);
      unsigned short* d0 = &lds[0][(w << 5) + (u << 3)][0];
      unsigned short* d1 = &lds[1][(w << 5) + (u << 3)][0];
      unsigned short* d2 = &lds[2][(w << 5) + (u << 3)][0];
      unsigned short* d3 = &lds[3][(w << 5) + (u << 3)][0];
      gl_lds16(q0p + src, d0);
      gl_lds16(q1p + src, d1);
      gl_lds16(k0p + src, d2);
      gl_lds16(k1p + src, d3);
    }
  }
  __syncthreads();   // compiler drains vmcnt before the barrier

  const int r16 = lane & 15, g = lane >> 4;
  const int qw = (w >> 1) << 6;   // wave's q half within block
  const int sw = (w & 1) << 6;    // wave's s half within block

  f32x4 accB[4][4] = {};
  f32x4 accS[4][4] = {};
  half8 aH[2][4], bH[2][4], tX[2][4];

  // fragment read: lane holds row (l&15), 8 f16 at k = (l>>4)*8 + ks*32
#define FRAG(p, rowbase, c_)                                                     \
  (*(const half8*)&lds[p][(rowbase) + r16][(((c_) ^ (((rowbase) + r16) & 7)) << 3)])

#pragma unroll
  for (int ks = 0; ks < 2; ++ks)
#pragma unroll
    for (int i = 0; i < 4; ++i) {
      aH[ks][i] = FRAG(0, qw + (i << 4), g + (ks << 2));
      bH[ks][i] = FRAG(2, sw + (i << 4), g + (ks << 2));
    }
  // pass B: Qh * Kh -> accB
#pragma unroll
  for (int ks = 0; ks < 2; ++ks)
#pragma unroll
    for (int i = 0; i < 4; ++i)
#pragma unroll
      for (int j = 0; j < 4; ++j)
        accB[i][j] = __builtin_amdgcn_mfma_f32_16x16x32_f16(aH[ks][i], bH[ks][j], accB[i][j], 0, 0, 0);
  // pass S1: Qh * Kl' -> accS
#pragma unroll
  for (int ks = 0; ks < 2; ++ks)
#pragma unroll
    for (int i = 0; i < 4; ++i)
      tX[ks][i] = FRAG(3, sw + (i << 4), g + (ks << 2));
#pragma unroll
  for (int ks = 0; ks < 2; ++ks)
#pragma unroll
    for (int i = 0; i < 4; ++i)
#pragma unroll
      for (int j = 0; j < 4; ++j)
        accS[i][j] = __builtin_amdgcn_mfma_f32_16x16x32_f16(aH[ks][i], tX[ks][j], accS[i][j], 0, 0, 0);
  // pass S2: Ql' * Kh -> accS
#pragma unroll
  for (int ks = 0; ks < 2; ++ks)
#pragma unroll
    for (int i = 0; i < 4; ++i)
      tX[ks][i] = FRAG(1, qw + (i << 4), g + (ks << 2));
#pragma unroll
  for (int ks = 0; ks < 2; ++ks)
#pragma unroll
    for (int i = 0; i < 4; ++i)
#pragma unroll
      for (int j = 0; j < 4; ++j)
        accS[i][j] = __builtin_amdgcn_mfma_f32_16x16x32_f16(tX[ks][i], bH[ks][j], accS[i][j], 0, 0, 0);
#undef FRAG

  // epilogue: C layout col = lane&15, row = (lane>>4)*4 + reg (verified m89/m91)
  const int sword = (s0 + sw) >> 6;
  const int sseg = (s0 + sw) >> 5;
#pragma unroll
  for (int i = 0; i < 4; ++i) {
#pragma unroll
    for (int r = 0; r < 4; ++r) {
      const int qg = q0 + qw + (i << 4) + (g << 2) + r;  // q within slice
      const u64 wm = mbits[((size_t)b * 2048 + qg) * 64 + sword];
      float s0v = (accB[i][0][r] + accS[i][0][r] * RINV) * 0.125f;
      float s1v = (accB[i][1][r] + accS[i][1][r] * RINV) * 0.125f;
      float s2v = (accB[i][2][r] + accS[i][2][r] * RINV) * 0.125f;
      float s3v = (accB[i][3][r] + accS[i][3][r] * RINV) * 0.125f;
      float v0 = ((wm >> (0 + r16)) & 1)  ? s0v : NEGV;
      float v1 = ((wm >> (16 + r16)) & 1) ? s1v : NEGV;
      float v2 = ((wm >> (32 + r16)) & 1) ? s2v : NEGV;
      float v3 = ((wm >> (48 + r16)) & 1) ? s3v : NEGV;
      float* rowp = sbuf + ((size_t)blockIdx.z * 2048 + qg) * 4096 + s0 + sw;
      rowp[r16] = v0;
      rowp[16 + r16] = v1;
      rowp[32 + r16] = v2;
      rowp[48 + r16] = v3;
      float m01 = fmaxf(v0, v1), m23 = fmaxf(v2, v3);
#pragma unroll
      for (int off = 8; off; off >>= 1) {
        m01 = fmaxf(m01, __shfl_xor(m01, off, 64));
        m23 = fmaxf(m23, __shfl_xor(m23, off, 64));
      }
      if (r16 == 0) {
        size_t sg = ((size_t)blockIdx.z * 2048 + qg) * 128 + sseg;
        segmax[sg] = m01;
        segmax[sg + 1] = m23;
      }
    }
  }
}

// ---- fused top-k + softmax + ctx: one WAVE per q-row (4 waves/block).
// MFMA scores locate candidates (DELTA margin -> superset of the true top-64);
// each candidate is rescored with a float64 dot over the TRUE fp32 q,k planes
// (qF,kF) — zero score noise relative to our projections. Candidate list and
// selection list are SEPARATE LDS buffers (no aliasing). ----
__global__ __launch_bounds__(256)
void topk_ctx_kernel(const float* __restrict__ sbuf, const float* __restrict__ segmax,
                     const float* __restrict__ vbuf,
                     const float* __restrict__ qF, const float* __restrict__ kF,
                     float* __restrict__ ctxbuf, int sl0) {
  const int sl = sl0 + blockIdx.y;
  const int b = sl >> 3, h = sl & 7;
  const int w = threadIdx.x >> 6, lane = threadIdx.x & 63;
  const int qi = (blockIdx.x << 2) + w;
  __shared__ u64 cand_lds[4][NCAND][64];       // 32 KB/block
  __shared__ u64 list_lds[4][LISTCAP];         // 8 KB/block (separate from cand)
  __shared__ alignas(16) float qrow[4][64];    // 1 KB
  u64* list = &list_lds[w][0];
  const u64 lmask_lt = (1ull << lane) - 1ull;

  const float* srow = sbuf + ((size_t)blockIdx.y * 2048 + qi) * 4096;

  // exact fp32 q row for this wave
  qrow[w][lane] = qF[((size_t)sl * 2048 + qi) * 64 + lane];
  __syncthreads();

  // segment maxes: 2 per lane (lane's own contiguous 64-elem region)
  float2 smv = *(const float2*)(segmax + ((size_t)blockIdx.y * 2048 + qi) * 128 + (lane << 1));
  u32 so0 = f2ord(smv.x), so1 = f2ord(smv.y);
  u32 mxo = so0 > so1 ? so0 : so1;
  u32 mno = so0 < so1 ? so0 : so1;
#pragma unroll
  for (int off = 32; off; off >>= 1) {
    u32 a = (u32)__shfl_xor((int)mxo, off, 64);
    u32 c = (u32)__shfl_xor((int)mno, off, 64);
    mxo = a > mxo ? a : mxo;
    mno = c < mno ? c : mno;
  }
  const float fm = ord2f(mxo);
  // T = largest v with count(segmax >= v) >= 64 (on MFMA scores)
  {
    u32 lo = mno, hi = mxo + 1;
    while (hi - lo > 1) {
      u32 mid = lo + ((hi - lo) >> 1);
      int c = __popcll(__ballot(so0 >= mid)) + __popcll(__ballot(so1 >= mid));
      if (c >= 64) lo = mid; else hi = mid;
    }
    mno = lo;  // reuse as ordT
  }
  const u32 ordT = mno;
  const float TfD = ord2f(ordT) - DELTA;   // margined candidate threshold

  // load only segments with segmax >= TfD; collect candidates x >= TfD
  int cnt = 0;
  const float* lbase = srow + (lane << 6);
#pragma unroll
  for (int reg = 0; reg < 2; ++reg) {
    bool active = (reg == 0) ? (smv.x >= TfD) : (smv.y >= TfD);
    if (active) {
      const float* rb = lbase + (reg << 5);
      float4 v0 = *(const float4*)(rb + 0);
      float4 v1 = *(const float4*)(rb + 4);
      float4 v2 = *(const float4*)(rb + 8);
      float4 v3 = *(const float4*)(rb + 12);
      float4 v4 = *(const float4*)(rb + 16);
      float4 v5 = *(const float4*)(rb + 20);
      float4 v6 = *(const float4*)(rb + 24);
      float4 v7 = *(const float4*)(rb + 28);
      float xs[32] = {v0.x, v0.y, v0.z, v0.w, v1.x, v1.y, v1.z, v1.w,
                      v2.x, v2.y, v2.z, v2.w, v3.x, v3.y, v3.z, v3.w,
                      v4.x, v4.y, v4.z, v4.w, v5.x, v5.y, v5.z, v5.w,
                      v6.x, v6.y, v6.z, v6.w, v7.x, v7.y, v7.z, v7.w};
#pragma unroll
      for (int cc = 0; cc < 32; ++cc) {
        if (xs[cc] >= TfD) {
          if (cnt < NCAND) {
            int sidx = (lane << 6) + (reg << 5) + cc;
            cand_lds[w][cnt][lane] = ((u64)f2ord(xs[cc]) << 32) | (u32)sidx;
          }
          cnt++;
        }
      }
    }
  }
  const bool fb = (__ballot(cnt > NCAND) != 0ull);

  float esum = 0.f;
  int nsel = 0;
  bool meanpath = false;

  if (!fb) {
    // exact rescoring: co[j] = ord of float64 dot(qF_row, kF_row)/8
    const float* kb = kF + (size_t)h * 4096 * 64;
    u32 co[NCAND];
    u32 mymax = 0u, mymin = 0xFFFFFFFFu;
#pragma unroll
    for (int j = 0; j < NCAND; ++j) {
      if (j < cnt) {
        const u32 sidx = (u32)cand_lds[w][j][lane];
        const float* kr = kb + (size_t)sidx * 64;
        double acc = 0.0;
#pragma unroll 4
        for (int dq = 0; dq < 16; ++dq) {
          float4 kv = *(const float4*)(kr + (dq << 2));
          float4 qv = *(const float4*)&qrow[w][dq << 2];
          acc += (double)kv.x * (double)qv.x;
          acc += (double)kv.y * (double)qv.y;
          acc += (double)kv.z * (double)qv.z;
          acc += (double)kv.w * (double)qv.w;
        }
        float s = (float)(acc * 0.125);
        u32 o = f2ord(s);
        co[j] = o;
        mymax = o > mymax ? o : mymax;
        mymin = o < mymin ? o : mymin;
      } else {
        co[j] = 0u;
      }
    }
    // wave-reduce bounds over rescored ords
#pragma unroll
    for (int off = 32; off; off >>= 1) {
      u32 a = (u32)__shfl_xor((int)mymax, off, 64);
      u32 c = (u32)__shfl_xor((int)mymin, off, 64);
      mymax = a > mymax ? a : mymax;
      mymin = c < mymin ? c : mymin;
    }
    const float fmr = ord2f(mymax);
    // binary search: largest lo with count(co >= lo) >= 64 (exact 64th-largest)
    u32 lo = mymin, hi = mymax + 1;
    while (hi - lo > 1) {
      u32 mid = lo + ((hi - lo) >> 1);
      int c = 0;
#pragma unroll
      for (int j = 0; j < NCAND; ++j)
        c += __popcll(__ballot(co[j] >= mid));
      if (c >= 64) lo = mid; else hi = mid;
    }
    // extraction in fixed j-order; ev from the rescored value
    int base = 0;
#pragma unroll
    for (int j = 0; j < NCAND; ++j) {
      bool pred = (j < cnt) && (co[j] >= lo);
      u64 m = __ballot(pred);
      int ofs = base + __popcll(m & lmask_lt);
      if (pred && ofs < LISTCAP) {
        u32 sidx = (u32)cand_lds[w][j][lane];
        float ev = __expf(ord2f(co[j]) - fmr);
        list[ofs] = ((u64)sidx << 32) | (u64)__float_as_uint(ev);
        esum += ev;
      }
      base += (int)__popcll(m);
    }
    nsel = base < LISTCAP ? base : LISTCAP;
  } else {
    // rare exact fallback: full binary search streaming the row (MFMA scores)
    u32 lo = ordT, hi = mxo + 1;
    while (hi - lo > 1) {
      u32 mid = lo + ((hi - lo) >> 1);
      float midf = ord2f(mid);
      int c = 0;
      for (int j = 0; j < 16; ++j) {
        float4 v = *(const float4*)(srow + (j << 8) + (lane << 2));
        c += __popcll(__ballot(v.x >= midf)) + __popcll(__ballot(v.y >= midf)) +
             __popcll(__ballot(v.z >= midf)) + __popcll(__ballot(v.w >= midf));
      }
      if (c >= 64) lo = mid; else hi = mid;
    }
    const float thrf = ord2f(lo);
    int base = 0;
    for (int j = 0; j < 16; ++j) {
      float4 v = *(const float4*)(srow + (j << 8) + (lane << 2));
      float xs[4] = {v.x, v.y, v.z, v.w};
#pragma unroll
      for (int cpos = 0; cpos < 4; ++cpos) {
        float x = xs[cpos];
        bool pred = (x >= thrf) && (x != NEGV);
        u64 m = __ballot(pred);
        int ofs = base + __popcll(m & lmask_lt);
        if (pred && ofs < LISTCAP) {
          int sidx = (j << 8) + (lane << 2) + cpos;
          float ev = __expf(x - fm);
          list[ofs] = ((u64)(u32)sidx << 32) | (u64)__float_as_uint(ev);
          esum += ev;
        }
        base += (int)__popcll(m);
      }
    }
    nsel = base < LISTCAP ? base : LISTCAP;
    if (base == 0) meanpath = true;  // fully masked row
  }

#pragma unroll
  for (int off = 32; off; off >>= 1) esum += __shfl_xor(esum, off, 64);
  const float* vb = vbuf + h * 64 + lane;
  float outv;
  if (!meanpath) {
    const float rs = 1.0f / esum;
    int pad = (8 - (nsel & 7)) & 7;
    if (lane < pad && nsel + lane < LISTCAP) list[nsel + lane] = 0;  // ev=+0, idx=0
    int n8 = nsel + pad;
    if (n8 > LISTCAP) n8 = LISTCAP;
    float a0 = 0.f, a1 = 0.f, a2 = 0.f, a3 = 0.f;
    float a4 = 0.f, a5 = 0.f, a6 = 0.f, a7 = 0.f;
    for (int g = 0; g < n8; g += 8) {
      u64 p0 = list[g + 0], p1 = list[g + 1], p2 = list[g + 2], p3 = list[g + 3];
      u64 p4 = list[g + 4], p5 = list[g + 5], p6 = list[g + 6], p7 = list[g + 7];
      a0 += __uint_as_float((u32)p0) * vb[(size_t)(p0 >> 32) * 512];
      a1 += __uint_as_float((u32)p1) * vb[(size_t)(p1 >> 32) * 512];
      a2 += __uint_as_float((u32)p2) * vb[(size_t)(p2 >> 32) * 512];
      a3 += __uint_as_float((u32)p3) * vb[(size_t)(p3 >> 32) * 512];
      a4 += __uint_as_float((u32)p4) * vb[(size_t)(p4 >> 32) * 512];
      a5 += __uint_as_float((u32)p5) * vb[(size_t)(p5 >> 32) * 512];
      a6 += __uint_as_float((u32)p6) * vb[(size_t)(p6 >> 32) * 512];
      a7 += __uint_as_float((u32)p7) * vb[(size_t)(p7 >> 32) * 512];
    }
    outv = (((a0 + a1) + (a2 + a3)) + ((a4 + a5) + (a6 + a7))) * rs;
  } else {
    float acc = 0.f;
    for (int s = 0; s < 4096; ++s) acc += vb[(size_t)s * 512];
    outv = acc * (1.0f / 4096.0f);
  }
  ctxbuf[((size_t)(b * 2048 + qi)) * 512 + h * 64 + lane] = outv;
}

extern "C" void kernel_launch(void* const* d_in, const int* in_sizes, int n_in,
                              void* d_out, int out_size, void* d_ws, size_t ws_size,
                              hipStream_t stream) {
  const float* main_in = (const float*)d_in[0];
  const float* side_in = (const float*)d_in[1];
  const int*   mask    = (const int*)d_in[2];
  const float* Wq = (const float*)d_in[3];
  const float* bq = (const float*)d_in[4];
  const float* Wk = (const float*)d_in[5];
  const float* bk = (const float*)d_in[6];
  const float* Wv = (const float*)d_in[7];
  const float* bv = (const float*)d_in[8];
  const float* Wo = (const float*)d_in[9];
  const float* bo = (const float*)d_in[10];
  float* out = (float*)d_out;

  char* ws = (char*)d_ws;
  float* vbuf = (float*)(ws);                                   // 8 MB
  float* ctxb = (float*)(ws + ((size_t)8 << 20));               // 8 MB
  unsigned short* qhp = (unsigned short*)(ws + ((size_t)16 << 20)); // 4 MB [16][2048][64]
  unsigned short* qlp = (unsigned short*)(ws + ((size_t)20 << 20)); // 4 MB
  unsigned short* khp = (unsigned short*)(ws + ((size_t)24 << 20)); // 4 MB [8][4096][64]
  unsigned short* klp = (unsigned short*)(ws + ((size_t)28 << 20)); // 4 MB
  u64* mbits  = (u64*)(ws + ((size_t)32 << 20));                // 2 MB
  float* qFp  = (float*)(ws + ((size_t)34 << 20));              // 8 MB [16][2048][64] fp32
  float* kFp  = (float*)(ws + ((size_t)42 << 20));              // 8 MB [8][4096][64]  fp32
  const size_t base = (size_t)50 << 20;
  const size_t sliceb = (size_t)2048 * 4096 * 4;    // 32 MB scores/slice
  const size_t segb   = (size_t)2048 * 128 * 4;     // 1 MB segmax/slice
  const size_t per = sliceb + segb;

  // choose nz (<=4) such that base + nz*per fits in ws_size
  int nz = 1;
  if (ws_size > base) {
    size_t m = (ws_size - base) / per;
    if (m >= 1) nz = (int)(m > 4 ? 4 : m);
  }
  float* sbuf = (float*)(ws + base);
  float* smax = (float*)(ws + base + (size_t)nz * sliceb);

  pack_mask<<<1024, 256, 0, stream>>>(mask, mbits);
  gemm_bias_split<<<dim3(8, 64), 256, 0, stream>>>(main_in, Wq, bq, qhp, qlp, qFp, 11);
  gemm_bias_split<<<dim3(8, 64), 256, 0, stream>>>(side_in, Wk, bk, khp, klp, kFp, 12);
  gemm_bias  <<<dim3(8, 64), 256, 0, stream>>>(side_in, Wv, bv, vbuf);

  for (int sl0 = 0; sl0 < 16; sl0 += nz) {
    int z = nz < (16 - sl0) ? nz : (16 - sl0);
    score_mfma     <<<dim3(32, 16, z), 256, 0, stream>>>(qhp, qlp, khp, klp, mbits, sbuf, smax, sl0);
    topk_ctx_kernel<<<dim3(512, z), 256, 0, stream>>>(sbuf, smax, vbuf,
                                                      qFp, kFp, ctxb, sl0);
  }

  gemm_bias<<<dim3(8, 64), 256, 0, stream>>>(ctxb, Wo, bo, out);
}

// Round 7
// 775.786 us; speedup vs baseline: 1.0657x; 1.0657x over previous
//
#include <hip/hip_runtime.h>
#include <stdint.h>

typedef uint32_t u32;
typedef unsigned long long u64;

#define NEGV (-1e9f)
#define NCAND 16
#define LISTCAP 256
#define RSCALE 2048.0f
#define RINV   (1.0f / 2048.0f)
#define DELTA  4e-3f

typedef __attribute__((ext_vector_type(8))) _Float16 half8;
typedef __attribute__((ext_vector_type(4))) float f32x4;

__device__ __forceinline__ u32 f2ord(float f) {
  u32 x = __float_as_uint(f);
  return (x & 0x80000000u) ? ~x : (x | 0x80000000u);
}
__device__ __forceinline__ float ord2f(u32 u) {
  u32 x = (u & 0x80000000u) ? (u ^ 0x80000000u) : ~u;
  return __uint_as_float(x);
}

// async global->LDS, 16B per lane. LDS dest = wave-uniform base + lane*16.
__device__ __forceinline__ void gl_lds16(const unsigned short* g, unsigned short* l) {
  __builtin_amdgcn_global_load_lds(
      (const __attribute__((address_space(1))) u32*)g,
      (__attribute__((address_space(3))) u32*)l, 16, 0, 0);
}

// ---- mask packer: int32 mask [2][2048][4096] -> u64 bits [2][2048][64] ----
__global__ __launch_bounds__(256)
void pack_mask(const int* __restrict__ mask, u64* __restrict__ mbits) {
  int w = blockIdx.x * 256 + threadIdx.x;
  const int4* p = (const int4*)(mask + (size_t)w * 64);
  u64 bits = 0;
#pragma unroll
  for (int j = 0; j < 16; ++j) {
    int4 m = p[j];
    if (m.x) bits |= 1ull << (j * 4 + 0);
    if (m.y) bits |= 1ull << (j * 4 + 1);
    if (m.z) bits |= 1ull << (j * 4 + 2);
    if (m.w) bits |= 1ull << (j * 4 + 3);
  }
  mbits[w] = bits;
}

// ---- C[M x 512] = A[M x 512] @ W[512 x 512] + bias (row-major out) ----
__global__ __launch_bounds__(256)
void gemm_bias(const float* __restrict__ A, const float* __restrict__ W,
               const float* __restrict__ bias, float* __restrict__ C) {
  __shared__ float As[16][68];
  __shared__ float Bs[16][64];
  const int tid = threadIdx.x;
  const int tx = tid & 15, ty = tid >> 4;
  const int n0 = blockIdx.x << 6, m0 = blockIdx.y << 6;
  float c[4][4] = {};
  for (int k0 = 0; k0 < 512; k0 += 16) {
    {
      const int row = tid >> 2, kp = (tid & 3) << 2;
      float4 av = *(const float4*)&A[(size_t)(m0 + row) * 512 + k0 + kp];
      As[kp + 0][row] = av.x;
      As[kp + 1][row] = av.y;
      As[kp + 2][row] = av.z;
      As[kp + 3][row] = av.w;
      const int kk = tid >> 4, np = (tid & 15) << 2;
      *(float4*)&Bs[kk][np] = *(const float4*)&W[(size_t)(k0 + kk) * 512 + n0 + np];
    }
    __syncthreads();
#pragma unroll
    for (int kk = 0; kk < 16; ++kk) {
      float4 a = *(const float4*)&As[kk][ty << 2];
      float4 b = *(const float4*)&Bs[kk][tx << 2];
      c[0][0] += a.x * b.x; c[0][1] += a.x * b.y; c[0][2] += a.x * b.z; c[0][3] += a.x * b.w;
      c[1][0] += a.y * b.x; c[1][1] += a.y * b.y; c[1][2] += a.y * b.z; c[1][3] += a.y * b.w;
      c[2][0] += a.z * b.x; c[2][1] += a.z * b.y; c[2][2] += a.z * b.z; c[2][3] += a.z * b.w;
      c[3][0] += a.w * b.x; c[3][1] += a.w * b.y; c[3][2] += a.w * b.z; c[3][3] += a.w * b.w;
    }
    __syncthreads();
  }
  float4 bv = *(const float4*)&bias[n0 + (tx << 2)];
#pragma unroll
  for (int i = 0; i < 4; ++i) {
    float4 o;
    o.x = c[i][0] + bv.x; o.y = c[i][1] + bv.y;
    o.z = c[i][2] + bv.z; o.w = c[i][3] + bv.w;
    *(float4*)&C[(size_t)(m0 + (ty << 2) + i) * 512 + n0 + (tx << 2)] = o;
  }
}

// ---- same GEMM math; epilogue writes (a) fp32 head-major plane Pf (exact
// projection values, used for candidate rescoring), (b) f16 hi plane,
// (c) f16 residual*2^11 plane (kept f16-normal; unscaled residuals ~1e-4 are
// f16-denormal and flush in the MFMA). Layout for all three:
// P[(m>>qsh)*8 + h][m & (QL-1)][d], d=0..63. ----
__global__ __launch_bounds__(256)
void gemm_bias_split(const float* __restrict__ A, const float* __restrict__ W,
                     const float* __restrict__ bias,
                     unsigned short* __restrict__ Ph, unsigned short* __restrict__ Pl,
                     float* __restrict__ Pf, int qsh) {
  __shared__ float As[16][68];
  __shared__ float Bs[16][64];
  const int tid = threadIdx.x;
  const int tx = tid & 15, ty = tid >> 4;
  const int n0 = blockIdx.x << 6, m0 = blockIdx.y << 6;
  float c[4][4] = {};
  for (int k0 = 0; k0 < 512; k0 += 16) {
    {
      const int row = tid >> 2, kp = (tid & 3) << 2;
      float4 av = *(const float4*)&A[(size_t)(m0 + row) * 512 + k0 + kp];
      As[kp + 0][row] = av.x;
      As[kp + 1][row] = av.y;
      As[kp + 2][row] = av.z;
      As[kp + 3][row] = av.w;
      const int kk = tid >> 4, np = (tid & 15) << 2;
      *(float4*)&Bs[kk][np] = *(const float4*)&W[(size_t)(k0 + kk) * 512 + n0 + np];
    }
    __syncthreads();
#pragma unroll
    for (int kk = 0; kk < 16; ++kk) {
      float4 a = *(const float4*)&As[kk][ty << 2];
      float4 b = *(const float4*)&Bs[kk][tx << 2];
      c[0][0] += a.x * b.x; c[0][1] += a.x * b.y; c[0][2] += a.x * b.z; c[0][3] += a.x * b.w;
      c[1][0] += a.y * b.x; c[1][1] += a.y * b.y; c[1][2] += a.y * b.z; c[1][3] += a.y * b.w;
      c[2][0] += a.z * b.x; c[2][1] += a.z * b.y; c[2][2] += a.z * b.z; c[2][3] += a.z * b.w;
      c[3][0] += a.w * b.x; c[3][1] += a.w * b.y; c[3][2] += a.w * b.z; c[3][3] += a.w * b.w;
    }
    __syncthreads();
  }
  float4 bv = *(const float4*)&bias[n0 + (tx << 2)];
  float bvv[4] = {bv.x, bv.y, bv.z, bv.w};
  const int h = blockIdx.x;           // n0 = h*64 since tile width == head width
  const int QL = 1 << qsh;
#pragma unroll
  for (int i = 0; i < 4; ++i) {
    const int m = m0 + (ty << 2) + i;
    const size_t base =
        (((size_t)((m >> qsh) * 8 + h)) * QL + (m & (QL - 1))) * 64 + (tx << 2);
    u64 hb = 0, lb = 0;
    float fv[4];
#pragma unroll
    for (int j = 0; j < 4; ++j) {
      float val = c[i][j] + bvv[j];
      fv[j] = val;
      union { _Float16 f; unsigned short u; } ch, cl;
      ch.f = (_Float16)val;                       // RN fp32->fp16
      float hf = (float)ch.f;
      cl.f = (_Float16)((val - hf) * RSCALE);     // exact diff, scaled to normal range
      hb |= (u64)ch.u << (16 * j);
      lb |= (u64)cl.u << (16 * j);
    }
    float4 fo;
    fo.x = fv[0]; fo.y = fv[1]; fo.z = fv[2]; fo.w = fv[3];
    *(u64*)&Ph[base] = hb;
    *(u64*)&Pl[base] = lb;
    *(float4*)&Pf[base] = fo;
  }
}

// ---- scores via MFMA f16x3 with scaled residuals: 128(q) x 128(s) tile per
// block, 4 waves each computing a 64x64 quadrant with mfma_f32_16x16x32_f16.
//   accB = Qh*Kh; accS = Qh*Kl' + Ql'*Kh; s = (accB + accS/2^11) * 0.125
// Scores used for candidate DISCOVERY only (DELTA-margined); selection +
// softmax use exact fp32/f64 rescoring in topk_ctx. ----
__global__ __launch_bounds__(256, 2)
void score_mfma(const unsigned short* __restrict__ qh, const unsigned short* __restrict__ ql,
                const unsigned short* __restrict__ kh, const unsigned short* __restrict__ kl,
                const u64* __restrict__ mbits, float* __restrict__ sbuf,
                float* __restrict__ segmax, int sl0) {
  __shared__ alignas(16) unsigned short lds[4][128][64];  // qh, ql, kh, kl = 64 KB
  const int sl = sl0 + blockIdx.z;
  const int b = sl >> 3, h = sl & 7;
  const int s0 = blockIdx.x << 7, q0 = blockIdx.y << 7;
  const int tid = threadIdx.x;
  const int lane = tid & 63, w = tid >> 6;

  const unsigned short* q0p = qh + ((size_t)sl * 2048 + q0) * 64;
  const unsigned short* q1p = ql + ((size_t)sl * 2048 + q0) * 64;
  const unsigned short* k0p = kh + ((size_t)h * 4096 + s0) * 64;
  const unsigned short* k1p = kl + ((size_t)h * 4096 + s0) * 64;

  // stage: wave w stages rows [w*32, w*32+32) of each plane; 8 rows (1 KB) per
  // instruction. LDS[row][p] <- global[row][p ^ (row&7)] (16B chunk units).
  {
    const int r8 = lane >> 3, pc = lane & 7;
#pragma unroll
    for (int u = 0; u < 4; ++u) {
      const int row = (w << 5) + (u << 3) + r8;
      const size_t src = (size_t)row * 64 + (size_t)((pc ^ (row & 7)) << 3);
      unsigned short* d0 = &lds[0][(w << 5) + (u << 3)][0];
      unsigned short* d1 = &lds[1][(w << 5) + (u << 3)][0];
      unsigned short* d2 = &lds[2][(w << 5) + (u << 3)][0];
      unsigned short* d3 = &lds[3][(w << 5) + (u << 3)][0];
      gl_lds16(q0p + src, d0);
      gl_lds16(q1p + src, d1);
      gl_lds16(k0p + src, d2);
      gl_lds16(k1p + src, d3);
    }
  }
  __syncthreads();   // compiler drains vmcnt before the barrier

  const int r16 = lane & 15, g = lane >> 4;
  const int qw = (w >> 1) << 6;   // wave's q half within block
  const int sw = (w & 1) << 6;    // wave's s half within block

  f32x4 accB[4][4] = {};
  f32x4 accS[4][4] = {};
  half8 aH[2][4], bH[2][4], tX[2][4];

  // fragment read: lane holds row (l&15), 8 f16 at k = (l>>4)*8 + ks*32
#define FRAG(p, rowbase, c_)                                                     \
  (*(const half8*)&lds[p][(rowbase) + r16][(((c_) ^ (((rowbase) + r16) & 7)) << 3)])

#pragma unroll
  for (int ks = 0; ks < 2; ++ks)
#pragma unroll
    for (int i = 0; i < 4; ++i) {
      aH[ks][i] = FRAG(0, qw + (i << 4), g + (ks << 2));
      bH[ks][i] = FRAG(2, sw + (i << 4), g + (ks << 2));
    }
  // pass B: Qh * Kh -> accB
#pragma unroll
  for (int ks = 0; ks < 2; ++ks)
#pragma unroll
    for (int i = 0; i < 4; ++i)
#pragma unroll
      for (int j = 0; j < 4; ++j)
        accB[i][j] = __builtin_amdgcn_mfma_f32_16x16x32_f16(aH[ks][i], bH[ks][j], accB[i][j], 0, 0, 0);
  // pass S1: Qh * Kl' -> accS
#pragma unroll
  for (int ks = 0; ks < 2; ++ks)
#pragma unroll
    for (int i = 0; i < 4; ++i)
      tX[ks][i] = FRAG(3, sw + (i << 4), g + (ks << 2));
#pragma unroll
  for (int ks = 0; ks < 2; ++ks)
#pragma unroll
    for (int i = 0; i < 4; ++i)
#pragma unroll
      for (int j = 0; j < 4; ++j)
        accS[i][j] = __builtin_amdgcn_mfma_f32_16x16x32_f16(aH[ks][i], tX[ks][j], accS[i][j], 0, 0, 0);
  // pass S2: Ql' * Kh -> accS
#pragma unroll
  for (int ks = 0; ks < 2; ++ks)
#pragma unroll
    for (int i = 0; i < 4; ++i)
      tX[ks][i] = FRAG(1, qw + (i << 4), g + (ks << 2));
#pragma unroll
  for (int ks = 0; ks < 2; ++ks)
#pragma unroll
    for (int i = 0; i < 4; ++i)
#pragma unroll
      for (int j = 0; j < 4; ++j)
        accS[i][j] = __builtin_amdgcn_mfma_f32_16x16x32_f16(tX[ks][i], bH[ks][j], accS[i][j], 0, 0, 0);
#undef FRAG

  // epilogue: C layout col = lane&15, row = (lane>>4)*4 + reg (verified m89/m91)
  const int sword = (s0 + sw) >> 6;
  const int sseg = (s0 + sw) >> 5;
#pragma unroll
  for (int i = 0; i < 4; ++i) {
#pragma unroll
    for (int r = 0; r < 4; ++r) {
      const int qg = q0 + qw + (i << 4) + (g << 2) + r;  // q within slice
      const u64 wm = mbits[((size_t)b * 2048 + qg) * 64 + sword];
      float s0v = (accB[i][0][r] + accS[i][0][r] * RINV) * 0.125f;
      float s1v = (accB[i][1][r] + accS[i][1][r] * RINV) * 0.125f;
      float s2v = (accB[i][2][r] + accS[i][2][r] * RINV) * 0.125f;
      float s3v = (accB[i][3][r] + accS[i][3][r] * RINV) * 0.125f;
      float v0 = ((wm >> (0 + r16)) & 1)  ? s0v : NEGV;
      float v1 = ((wm >> (16 + r16)) & 1) ? s1v : NEGV;
      float v2 = ((wm >> (32 + r16)) & 1) ? s2v : NEGV;
      float v3 = ((wm >> (48 + r16)) & 1) ? s3v : NEGV;
      float* rowp = sbuf + ((size_t)blockIdx.z * 2048 + qg) * 4096 + s0 + sw;
      rowp[r16] = v0;
      rowp[16 + r16] = v1;
      rowp[32 + r16] = v2;
      rowp[48 + r16] = v3;
      float m01 = fmaxf(v0, v1), m23 = fmaxf(v2, v3);
#pragma unroll
      for (int off = 8; off; off >>= 1) {
        m01 = fmaxf(m01, __shfl_xor(m01, off, 64));
        m23 = fmaxf(m23, __shfl_xor(m23, off, 64));
      }
      if (r16 == 0) {
        size_t sg = ((size_t)blockIdx.z * 2048 + qg) * 128 + sseg;
        segmax[sg] = m01;
        segmax[sg + 1] = m23;
      }
    }
  }
}

// ---- fused top-k + softmax + ctx: one WAVE per q-row (4 waves/block).
// MFMA scores locate candidates (DELTA margin -> superset of the true top-64);
// each candidate is rescored with a float64 dot over the TRUE fp32 q,k planes
// (qF,kF). cand_lds stores ONLY the u32 sidx (the MFMA ord was dead data) —
// LDS 41984->~25.9 KB lifts occupancy 3->6 blocks/CU for this latency-bound
// kernel. ----
__global__ __launch_bounds__(256)
void topk_ctx_kernel(const float* __restrict__ sbuf, const float* __restrict__ segmax,
                     const float* __restrict__ vbuf,
                     const float* __restrict__ qF, const float* __restrict__ kF,
                     float* __restrict__ ctxbuf, int sl0) {
  const int sl = sl0 + blockIdx.y;
  const int b = sl >> 3, h = sl & 7;
  const int w = threadIdx.x >> 6, lane = threadIdx.x & 63;
  const int qi = (blockIdx.x << 2) + w;
  __shared__ u32 cand_lds[4][NCAND][64];       // 16 KB/block (sidx only)
  __shared__ u64 list_lds[4][LISTCAP];         // 8 KB/block
  __shared__ alignas(16) float qrow[4][64];    // 1 KB
  u64* list = &list_lds[w][0];
  const u64 lmask_lt = (1ull << lane) - 1ull;

  const float* srow = sbuf + ((size_t)blockIdx.y * 2048 + qi) * 4096;

  // exact fp32 q row for this wave
  qrow[w][lane] = qF[((size_t)sl * 2048 + qi) * 64 + lane];
  __syncthreads();

  // segment maxes: 2 per lane (lane's own contiguous 64-elem region)
  float2 smv = *(const float2*)(segmax + ((size_t)blockIdx.y * 2048 + qi) * 128 + (lane << 1));
  u32 so0 = f2ord(smv.x), so1 = f2ord(smv.y);
  u32 mxo = so0 > so1 ? so0 : so1;
  u32 mno = so0 < so1 ? so0 : so1;
#pragma unroll
  for (int off = 32; off; off >>= 1) {
    u32 a = (u32)__shfl_xor((int)mxo, off, 64);
    u32 c = (u32)__shfl_xor((int)mno, off, 64);
    mxo = a > mxo ? a : mxo;
    mno = c < mno ? c : mno;
  }
  const float fm = ord2f(mxo);
  // T = largest v with count(segmax >= v) >= 64 (on MFMA scores)
  {
    u32 lo = mno, hi = mxo + 1;
    while (hi - lo > 1) {
      u32 mid = lo + ((hi - lo) >> 1);
      int c = __popcll(__ballot(so0 >= mid)) + __popcll(__ballot(so1 >= mid));
      if (c >= 64) lo = mid; else hi = mid;
    }
    mno = lo;  // reuse as ordT
  }
  const u32 ordT = mno;
  const float TfD = ord2f(ordT) - DELTA;   // margined candidate threshold

  // load only segments with segmax >= TfD; collect candidates x >= TfD
  int cnt = 0;
  const float* lbase = srow + (lane << 6);
#pragma unroll
  for (int reg = 0; reg < 2; ++reg) {
    bool active = (reg == 0) ? (smv.x >= TfD) : (smv.y >= TfD);
    if (active) {
      const float* rb = lbase + (reg << 5);
      float4 v0 = *(const float4*)(rb + 0);
      float4 v1 = *(const float4*)(rb + 4);
      float4 v2 = *(const float4*)(rb + 8);
      float4 v3 = *(const float4*)(rb + 12);
      float4 v4 = *(const float4*)(rb + 16);
      float4 v5 = *(const float4*)(rb + 20);
      float4 v6 = *(const float4*)(rb + 24);
      float4 v7 = *(const float4*)(rb + 28);
      float xs[32] = {v0.x, v0.y, v0.z, v0.w, v1.x, v1.y, v1.z, v1.w,
                      v2.x, v2.y, v2.z, v2.w, v3.x, v3.y, v3.z, v3.w,
                      v4.x, v4.y, v4.z, v4.w, v5.x, v5.y, v5.z, v5.w,
                      v6.x, v6.y, v6.z, v6.w, v7.x, v7.y, v7.z, v7.w};
#pragma unroll
      for (int cc = 0; cc < 32; ++cc) {
        if (xs[cc] >= TfD) {
          if (cnt < NCAND) {
            int sidx = (lane << 6) + (reg << 5) + cc;
            cand_lds[w][cnt][lane] = (u32)sidx;
          }
          cnt++;
        }
      }
    }
  }
  const bool fb = (__ballot(cnt > NCAND) != 0ull);

  float esum = 0.f;
  int nsel = 0;
  bool meanpath = false;

  if (!fb) {
    // exact rescoring: co[j] = ord of float64 dot(qF_row, kF_row)/8
    const float* kb = kF + (size_t)h * 4096 * 64;
    u32 co[NCAND];
    u32 mymax = 0u, mymin = 0xFFFFFFFFu;
#pragma unroll
    for (int j = 0; j < NCAND; ++j) {
      if (j < cnt) {
        const u32 sidx = cand_lds[w][j][lane];
        const float* kr = kb + (size_t)sidx * 64;
        double acc = 0.0;
#pragma unroll 4
        for (int dq = 0; dq < 16; ++dq) {
          float4 kv = *(const float4*)(kr + (dq << 2));
          float4 qv = *(const float4*)&qrow[w][dq << 2];
          acc += (double)kv.x * (double)qv.x;
          acc += (double)kv.y * (double)qv.y;
          acc += (double)kv.z * (double)qv.z;
          acc += (double)kv.w * (double)qv.w;
        }
        float s = (float)(acc * 0.125);
        u32 o = f2ord(s);
        co[j] = o;
        mymax = o > mymax ? o : mymax;
        mymin = o < mymin ? o : mymin;
      } else {
        co[j] = 0u;
      }
    }
    // wave-reduce bounds over rescored ords
#pragma unroll
    for (int off = 32; off; off >>= 1) {
      u32 a = (u32)__shfl_xor((int)mymax, off, 64);
      u32 c = (u32)__shfl_xor((int)mymin, off, 64);
      mymax = a > mymax ? a : mymax;
      mymin = c < mymin ? c : mymin;
    }
    const float fmr = ord2f(mymax);
    // binary search: largest lo with count(co >= lo) >= 64 (exact 64th-largest)
    u32 lo = mymin, hi = mymax + 1;
    while (hi - lo > 1) {
      u32 mid = lo + ((hi - lo) >> 1);
      int c = 0;
#pragma unroll
      for (int j = 0; j < NCAND; ++j)
        c += __popcll(__ballot(co[j] >= mid));
      if (c >= 64) lo = mid; else hi = mid;
    }
    // extraction in fixed j-order; ev from the rescored value
    int base = 0;
#pragma unroll
    for (int j = 0; j < NCAND; ++j) {
      bool pred = (j < cnt) && (co[j] >= lo);
      u64 m = __ballot(pred);
      int ofs = base + __popcll(m & lmask_lt);
      if (pred && ofs < LISTCAP) {
        u32 sidx = cand_lds[w][j][lane];
        float ev = __expf(ord2f(co[j]) - fmr);
        list[ofs] = ((u64)sidx << 32) | (u64)__float_as_uint(ev);
        esum += ev;
      }
      base += (int)__popcll(m);
    }
    nsel = base < LISTCAP ? base : LISTCAP;
  } else {
    // rare exact fallback: full binary search streaming the row (MFMA scores)
    u32 lo = ordT, hi = mxo + 1;
    while (hi - lo > 1) {
      u32 mid = lo + ((hi - lo) >> 1);
      float midf = ord2f(mid);
      int c = 0;
      for (int j = 0; j < 16; ++j) {
        float4 v = *(const float4*)(srow + (j << 8) + (lane << 2));
        c += __popcll(__ballot(v.x >= midf)) + __popcll(__ballot(v.y >= midf)) +
             __popcll(__ballot(v.z >= midf)) + __popcll(__ballot(v.w >= midf));
      }
      if (c >= 64) lo = mid; else hi = mid;
    }
    const float thrf = ord2f(lo);
    int base = 0;
    for (int j = 0; j < 16; ++j) {
      float4 v = *(const float4*)(srow + (j << 8) + (lane << 2));
      float xs[4] = {v.x, v.y, v.z, v.w};
#pragma unroll
      for (int cpos = 0; cpos < 4; ++cpos) {
        float x = xs[cpos];
        bool pred = (x >= thrf) && (x != NEGV);
        u64 m = __ballot(pred);
        int ofs = base + __popcll(m & lmask_lt);
        if (pred && ofs < LISTCAP) {
          int sidx = (j << 8) + (lane << 2) + cpos;
          float ev = __expf(x - fm);
          list[ofs] = ((u64)(u32)sidx << 32) | (u64)__float_as_uint(ev);
          esum += ev;
        }
        base += (int)__popcll(m);
      }
    }
    nsel = base < LISTCAP ? base : LISTCAP;
    if (base == 0) meanpath = true;  // fully masked row
  }

#pragma unroll
  for (int off = 32; off; off >>= 1) esum += __shfl_xor(esum, off, 64);
  const float* vb = vbuf + h * 64 + lane;
  float outv;
  if (!meanpath) {
    const float rs = 1.0f / esum;
    int pad = (8 - (nsel & 7)) & 7;
    if (lane < pad && nsel + lane < LISTCAP) list[nsel + lane] = 0;  // ev=+0, idx=0
    int n8 = nsel + pad;
    if (n8 > LISTCAP) n8 = LISTCAP;
    float a0 = 0.f, a1 = 0.f, a2 = 0.f, a3 = 0.f;
    float a4 = 0.f, a5 = 0.f, a6 = 0.f, a7 = 0.f;
    for (int g = 0; g < n8; g += 8) {
      u64 p0 = list[g + 0], p1 = list[g + 1], p2 = list[g + 2], p3 = list[g + 3];
      u64 p4 = list[g + 4], p5 = list[g + 5], p6 = list[g + 6], p7 = list[g + 7];
      a0 += __uint_as_float((u32)p0) * vb[(size_t)(p0 >> 32) * 512];
      a1 += __uint_as_float((u32)p1) * vb[(size_t)(p1 >> 32) * 512];
      a2 += __uint_as_float((u32)p2) * vb[(size_t)(p2 >> 32) * 512];
      a3 += __uint_as_float((u32)p3) * vb[(size_t)(p3 >> 32) * 512];
      a4 += __uint_as_float((u32)p4) * vb[(size_t)(p4 >> 32) * 512];
      a5 += __uint_as_float((u32)p5) * vb[(size_t)(p5 >> 32) * 512];
      a6 += __uint_as_float((u32)p6) * vb[(size_t)(p6 >> 32) * 512];
      a7 += __uint_as_float((u32)p7) * vb[(size_t)(p7 >> 32) * 512];
    }
    outv = (((a0 + a1) + (a2 + a3)) + ((a4 + a5) + (a6 + a7))) * rs;
  } else {
    float acc = 0.f;
    for (int s = 0; s < 4096; ++s) acc += vb[(size_t)s * 512];
    outv = acc * (1.0f / 4096.0f);
  }
  ctxbuf[((size_t)(b * 2048 + qi)) * 512 + h * 64 + lane] = outv;
}

extern "C" void kernel_launch(void* const* d_in, const int* in_sizes, int n_in,
                              void* d_out, int out_size, void* d_ws, size_t ws_size,
                              hipStream_t stream) {
  const float* main_in = (const float*)d_in[0];
  const float* side_in = (const float*)d_in[1];
  const int*   mask    = (const int*)d_in[2];
  const float* Wq = (const float*)d_in[3];
  const float* bq = (const float*)d_in[4];
  const float* Wk = (const float*)d_in[5];
  const float* bk = (const float*)d_in[6];
  const float* Wv = (const float*)d_in[7];
  const float* bv = (const float*)d_in[8];
  const float* Wo = (const float*)d_in[9];
  const float* bo = (const float*)d_in[10];
  float* out = (float*)d_out;

  char* ws = (char*)d_ws;
  float* vbuf = (float*)(ws);                                   // 8 MB
  float* ctxb = (float*)(ws + ((size_t)8 << 20));               // 8 MB
  unsigned short* qhp = (unsigned short*)(ws + ((size_t)16 << 20)); // 4 MB [16][2048][64]
  unsigned short* qlp = (unsigned short*)(ws + ((size_t)20 << 20)); // 4 MB
  unsigned short* khp = (unsigned short*)(ws + ((size_t)24 << 20)); // 4 MB [8][4096][64]
  unsigned short* klp = (unsigned short*)(ws + ((size_t)28 << 20)); // 4 MB
  u64* mbits  = (u64*)(ws + ((size_t)32 << 20));                // 2 MB
  float* qFp  = (float*)(ws + ((size_t)34 << 20));              // 8 MB [16][2048][64] fp32
  float* kFp  = (float*)(ws + ((size_t)42 << 20));              // 8 MB [8][4096][64]  fp32
  const size_t base = (size_t)50 << 20;
  const size_t sliceb = (size_t)2048 * 4096 * 4;    // 32 MB scores/slice
  const size_t segb   = (size_t)2048 * 128 * 4;     // 1 MB segmax/slice
  const size_t per = sliceb + segb;

  // choose nz (<=4) such that base + nz*per fits in ws_size
  int nz = 1;
  if (ws_size > base) {
    size_t m = (ws_size - base) / per;
    if (m >= 1) nz = (int)(m > 4 ? 4 : m);
  }
  float* sbuf = (float*)(ws + base);
  float* smax = (float*)(ws + base + (size_t)nz * sliceb);

  pack_mask<<<1024, 256, 0, stream>>>(mask, mbits);
  gemm_bias_split<<<dim3(8, 64), 256, 0, stream>>>(main_in, Wq, bq, qhp, qlp, qFp, 11);
  gemm_bias_split<<<dim3(8, 64), 256, 0, stream>>>(side_in, Wk, bk, khp, klp, kFp, 12);
  gemm_bias  <<<dim3(8, 64), 256, 0, stream>>>(side_in, Wv, bv, vbuf);

  for (int sl0 = 0; sl0 < 16; sl0 += nz) {
    int z = nz < (16 - sl0) ? nz : (16 - sl0);
    score_mfma     <<<dim3(32, 16, z), 256, 0, stream>>>(qhp, qlp, khp, klp, mbits, sbuf, smax, sl0);
    topk_ctx_kernel<<<dim3(512, z), 256, 0, stream>>>(sbuf, smax, vbuf,
                                                      qFp, kFp, ctxb, sl0);
  }

  gemm_bias<<<dim3(8, 64), 256, 0, stream>>>(ctxb, Wo, bo, out);
}